// Round 3
// baseline (256.307 us; speedup 1.0000x reference)
//
#include <hip/hip_runtime.h>
#include <hip/hip_bf16.h>

#define B_ 2
#define L_ 4096
#define DIM_ 512
#define HEADS_ 8
#define HDIM_ 64
#define KS_ 33

typedef __bf16 bf16;
typedef __bf16 bf16x8 __attribute__((ext_vector_type(8)));
typedef float f32x4 __attribute__((ext_vector_type(4)));

// fp32 -> bf16 convert (inputs are fp32 per reference; proven by R1/R2 evidence)
__global__ void cvt_to_bf16(const float* __restrict__ src, bf16* __restrict__ dst,
                            int n)
{
    int i = blockIdx.x * blockDim.x + threadIdx.x;
    if (i < n) dst[i] = (bf16)src[i];
}

// ---------------------------------------------------------------------------
// C[M,N] = A[M,K] * W[N,K]^T + bias[N]; bf16 in, OutT out, fp32 accumulate.
// Block = 256 threads (4 waves, 2x2), tile 128x128, BK=64.
// MFMA 16x16x32 bf16. LDS rows padded +8 bf16 -> 2-way bank aliasing (free).
// ---------------------------------------------------------------------------
template <typename OutT>
__global__ __launch_bounds__(256)
void gemm_nt_bias(const bf16* __restrict__ A, const bf16* __restrict__ W,
                  const bf16* __restrict__ bias, OutT* __restrict__ C,
                  int M, int N, int K)
{
    __shared__ bf16 As[128][72];
    __shared__ bf16 Bs[128][72];

    const int tid  = threadIdx.x;
    const int wave = tid >> 6;
    const int lane = tid & 63;
    const int wm   = (wave >> 1) * 64;
    const int wn   = (wave & 1) * 64;
    const int l16  = lane & 15;
    const int quad = lane >> 4;

    const int row0 = blockIdx.x * 128;
    const int col0 = blockIdx.y * 128;

    f32x4 acc[4][4] = {};

    for (int k0 = 0; k0 < K; k0 += 64) {
        #pragma unroll
        for (int it = 0; it < 4; ++it) {
            int idx = it * 256 + tid;      // 0..1023
            int r   = idx >> 3;
            int c   = (idx & 7) * 8;
            *(bf16x8*)(&As[r][c]) =
                *(const bf16x8*)(&A[(size_t)(row0 + r) * K + k0 + c]);
            *(bf16x8*)(&Bs[r][c]) =
                *(const bf16x8*)(&W[(size_t)(col0 + r) * K + k0 + c]);
        }
        __syncthreads();

        #pragma unroll
        for (int ks = 0; ks < 2; ++ks) {
            bf16x8 af[4], bfr[4];
            #pragma unroll
            for (int i = 0; i < 4; ++i) {
                af[i]  = *(const bf16x8*)(&As[wm + i * 16 + l16][ks * 32 + quad * 8]);
                bfr[i] = *(const bf16x8*)(&Bs[wn + i * 16 + l16][ks * 32 + quad * 8]);
            }
            #pragma unroll
            for (int mi = 0; mi < 4; ++mi)
                #pragma unroll
                for (int ni = 0; ni < 4; ++ni)
                    acc[mi][ni] = __builtin_amdgcn_mfma_f32_16x16x32_bf16(
                        af[mi], bfr[ni], acc[mi][ni], 0, 0, 0);
        }
        __syncthreads();
    }

    // C/D layout: col = lane&15, row = quad*4 + reg (m89/m91-verified)
    #pragma unroll
    for (int ni = 0; ni < 4; ++ni) {
        int n = col0 + wn + ni * 16 + l16;
        float bv = (float)bias[n];
        #pragma unroll
        for (int mi = 0; mi < 4; ++mi) {
            int mrow = row0 + wm + mi * 16 + quad * 4;
            #pragma unroll
            for (int r = 0; r < 4; ++r)
                C[(size_t)(mrow + r) * N + n] = (OutT)(acc[mi][ni][r] + bv);
        }
    }
}

// ---------------------------------------------------------------------------
// One wave per (b, h, l). lane = head dim (HDIM==64==wave width).
// Two-pass softmax: 33 scores via butterfly reductions, then weighted V sum.
// Window clamped: start = clip(l-16, 0, L-33) -> always exactly 33 keys.
// ---------------------------------------------------------------------------
__global__ __launch_bounds__(256)
void na1d_attn(const bf16* __restrict__ qkv, bf16* __restrict__ att)
{
    const int gwave = blockIdx.x * 4 + (threadIdx.x >> 6);
    const int lane  = threadIdx.x & 63;
    const int l  = gwave & (L_ - 1);
    const int bh = gwave >> 12;           // L = 4096 = 2^12
    const int h  = bh & (HEADS_ - 1);
    const int b  = bh >> 3;

    int start = l - KS_ / 2;
    if (start < 0) start = 0;
    if (start > L_ - KS_) start = L_ - KS_;

    const size_t rs = 3 * DIM_;  // 1536 qkv row stride
    const bf16* qrow  = qkv + (size_t)(b * L_ + l) * rs + h * HDIM_;
    const bf16* kbase = qkv + (size_t)(b * L_ + start) * rs + DIM_ + h * HDIM_;
    const bf16* vbase = kbase + DIM_;

    const float q = (float)qrow[lane] * 0.125f;  // SCALE = 64^-0.5

    float sc[KS_];
    #pragma unroll
    for (int j = 0; j < KS_; ++j) {
        float p = q * (float)kbase[(size_t)j * rs + lane];
        #pragma unroll
        for (int off = 32; off; off >>= 1)
            p += __shfl_xor(p, off, 64);
        sc[j] = p;
    }
    float m = sc[0];
    #pragma unroll
    for (int j = 1; j < KS_; ++j) m = fmaxf(m, sc[j]);
    float den = 0.f;
    #pragma unroll
    for (int j = 0; j < KS_; ++j) { sc[j] = __expf(sc[j] - m); den += sc[j]; }
    float acc = 0.f;
    #pragma unroll
    for (int j = 0; j < KS_; ++j)
        acc += sc[j] * (float)vbase[(size_t)j * rs + lane];
    acc /= den;

    att[(size_t)(b * L_ + l) * DIM_ + h * HDIM_ + lane] = (bf16)acc;
}

extern "C" void kernel_launch(void* const* d_in, const int* in_sizes, int n_in,
                              void* d_out, int out_size, void* d_ws, size_t ws_size,
                              hipStream_t stream) {
    const int n_x  = B_ * L_ * DIM_;       // 4194304
    const int n_wq = 3 * DIM_ * DIM_;      // 786432
    const int n_bq = 3 * DIM_;             // 1536
    const int n_wp = DIM_ * DIM_;          // 262144
    const int n_bp = DIM_;                 // 512

    char* ws = (char*)d_ws;
    bf16* xb  = (bf16*)ws;
    bf16* wqb = xb  + n_x;
    bf16* bqb = wqb + n_wq;
    bf16* wpb = bqb + n_bq;
    bf16* bpb = wpb + n_wp;
    bf16* qkv = bpb + n_bp;                          // 8192 x 1536
    bf16* att = qkv + (size_t)8192 * 1536;           // 8192 x 512

    float* out = (float*)d_out;            // reference output dtype = float32
    const int M = B_ * L_;  // 8192

    cvt_to_bf16<<<(n_x  + 255) / 256, 256, 0, stream>>>((const float*)d_in[0], xb,  n_x);
    cvt_to_bf16<<<(n_wq + 255) / 256, 256, 0, stream>>>((const float*)d_in[1], wqb, n_wq);
    cvt_to_bf16<<<(n_bq + 255) / 256, 256, 0, stream>>>((const float*)d_in[2], bqb, n_bq);
    cvt_to_bf16<<<(n_wp + 255) / 256, 256, 0, stream>>>((const float*)d_in[3], wpb, n_wp);
    cvt_to_bf16<<<(n_bp + 255) / 256, 256, 0, stream>>>((const float*)d_in[4], bpb, n_bp);

    gemm_nt_bias<bf16><<<dim3(M / 128, (3 * DIM_) / 128), 256, 0, stream>>>(
        xb, wqb, bqb, qkv, M, 3 * DIM_, DIM_);

    na1d_attn<<<dim3((B_ * HEADS_ * L_) / 4), 256, 0, stream>>>(qkv, att);

    gemm_nt_bias<float><<<dim3(M / 128, DIM_ / 128), 256, 0, stream>>>(
        att, wpb, bpb, out, M, DIM_, DIM_);
}

// Round 4
// 135.416 us; speedup vs baseline: 1.8927x; 1.8927x over previous
//
#include <hip/hip_runtime.h>
#include <hip/hip_bf16.h>

#define B_ 2
#define L_ 4096
#define DIM_ 512
#define HEADS_ 8
#define HDIM_ 64
#define KS_ 33

typedef __bf16 bf16;
typedef __bf16 bf16x4 __attribute__((ext_vector_type(4)));
typedef __bf16 bf16x8 __attribute__((ext_vector_type(8)));
typedef float f32x4 __attribute__((ext_vector_type(4)));

// fp32 -> bf16 convert (inputs are fp32 per reference)
__global__ void cvt_to_bf16(const float* __restrict__ src, bf16* __restrict__ dst,
                            int n)
{
    int i = blockIdx.x * blockDim.x + threadIdx.x;
    if (i < n) dst[i] = (bf16)src[i];
}

// ---------------------------------------------------------------------------
// C[M,N] = A[M,K] * W[N,K]^T + bias[N]; bf16 in, OutT out, fp32 accumulate.
// Block = 256 threads (4 waves, 2x2), tile 128x128, BK=64. (passing R3 kernel)
// ---------------------------------------------------------------------------
template <typename OutT>
__global__ __launch_bounds__(256)
void gemm_nt_bias(const bf16* __restrict__ A, const bf16* __restrict__ W,
                  const bf16* __restrict__ bias, OutT* __restrict__ C,
                  int M, int N, int K)
{
    __shared__ bf16 As[128][72];
    __shared__ bf16 Bs[128][72];

    const int tid  = threadIdx.x;
    const int wave = tid >> 6;
    const int lane = tid & 63;
    const int wm   = (wave >> 1) * 64;
    const int wn   = (wave & 1) * 64;
    const int l16  = lane & 15;
    const int quad = lane >> 4;

    const int row0 = blockIdx.x * 128;
    const int col0 = blockIdx.y * 128;

    f32x4 acc[4][4] = {};

    for (int k0 = 0; k0 < K; k0 += 64) {
        #pragma unroll
        for (int it = 0; it < 4; ++it) {
            int idx = it * 256 + tid;
            int r   = idx >> 3;
            int c   = (idx & 7) * 8;
            *(bf16x8*)(&As[r][c]) =
                *(const bf16x8*)(&A[(size_t)(row0 + r) * K + k0 + c]);
            *(bf16x8*)(&Bs[r][c]) =
                *(const bf16x8*)(&W[(size_t)(col0 + r) * K + k0 + c]);
        }
        __syncthreads();

        #pragma unroll
        for (int ks = 0; ks < 2; ++ks) {
            bf16x8 af[4], bfr[4];
            #pragma unroll
            for (int i = 0; i < 4; ++i) {
                af[i]  = *(const bf16x8*)(&As[wm + i * 16 + l16][ks * 32 + quad * 8]);
                bfr[i] = *(const bf16x8*)(&Bs[wn + i * 16 + l16][ks * 32 + quad * 8]);
            }
            #pragma unroll
            for (int mi = 0; mi < 4; ++mi)
                #pragma unroll
                for (int ni = 0; ni < 4; ++ni)
                    acc[mi][ni] = __builtin_amdgcn_mfma_f32_16x16x32_bf16(
                        af[mi], bfr[ni], acc[mi][ni], 0, 0, 0);
        }
        __syncthreads();
    }

    #pragma unroll
    for (int ni = 0; ni < 4; ++ni) {
        int n = col0 + wn + ni * 16 + l16;
        float bv = (float)bias[n];
        #pragma unroll
        for (int mi = 0; mi < 4; ++mi) {
            int mrow = row0 + wm + mi * 16 + quad * 4;
            #pragma unroll
            for (int r = 0; r < 4; ++r)
                C[(size_t)(mrow + r) * N + n] = (OutT)(acc[mi][ni][r] + bv);
        }
    }
}

// ---------------------------------------------------------------------------
// MFMA neighborhood attention. One wave per 16 consecutive queries of one
// (b,h). Window union of 16 queries spans <= 48 keys starting at
// k_base = clamp(q0-16, 0, L-33); per-query offset off in [0,15].
//   S[16q][48k] = 3x mfma(Q_frag, K_frag)   (frags straight from global,
//       operand layout rows=lane&15, k=quad*8+j — proven by the R3 GEMM)
//   mask (j<off || j>off+32) -> -1e30; softmax per row (quad-local butterfly,
//       C-layout row = quad*4+r, col = lane&15 — m89/m91-verified)
//   P normalized, through per-wave LDS [16][72] (C->A layout transform),
//   cols 48..63 zeroed.  O[16q][64d] = 4 d-tiles x 2 mfma(P_frag, Vt_frag),
//   Vt frags gathered per-element from global (L2-resident).
// Masked/padded keys: P=0 exactly; OOB key rows stay inside d_ws (finite
// bf16 patterns, never NaN) so 0*garbage = 0.
// ---------------------------------------------------------------------------
__global__ __launch_bounds__(256)
void na1d_attn_mfma(const bf16* __restrict__ qkv, bf16* __restrict__ att)
{
    __shared__ bf16 Plds[4][16][72];

    const int wave = threadIdx.x >> 6;
    const int lane = threadIdx.x & 63;
    const int l16  = lane & 15;
    const int quad = lane >> 4;

    const int wid = blockIdx.x * 4 + wave;   // 0..4095
    const int qg  = wid & 255;               // query group within (b,h)
    const int bh  = wid >> 8;                // b*8 + h
    const int h   = bh & 7;
    const int b   = bh >> 3;
    const int q0  = qg * 16;

    int k_base = q0 - 16;
    if (k_base < 0) k_base = 0;
    if (k_base > L_ - KS_) k_base = L_ - KS_;

    const size_t rs = 3 * DIM_;  // 1536

    // ---- Q fragments (A-operand: m = l16 = query, k = quad*8+j) ----
    const bf16* qptr = qkv + (size_t)(b * L_ + q0 + l16) * rs + h * HDIM_ + quad * 8;
    bf16x8 qf0 = *(const bf16x8*)(qptr);
    bf16x8 qf1 = *(const bf16x8*)(qptr + 32);

    // ---- S = Q K^T : 3 key tiles ----
    const bf16* kcol = qkv + (size_t)(b * L_ + k_base) * rs + DIM_ + h * HDIM_;
    f32x4 s[3] = {};
    #pragma unroll
    for (int t = 0; t < 3; ++t) {
        const bf16* kptr = kcol + (size_t)(t * 16 + l16) * rs + quad * 8;
        bf16x8 kf0 = *(const bf16x8*)(kptr);
        bf16x8 kf1 = *(const bf16x8*)(kptr + 32);
        s[t] = __builtin_amdgcn_mfma_f32_16x16x32_bf16(qf0, kf0, s[t], 0, 0, 0);
        s[t] = __builtin_amdgcn_mfma_f32_16x16x32_bf16(qf1, kf1, s[t], 0, 0, 0);
    }

    // ---- mask + scale ----
    int offr[4];
    #pragma unroll
    for (int r = 0; r < 4; ++r) {
        int lq = q0 + quad * 4 + r;
        int st = lq - KS_ / 2;
        if (st < 0) st = 0;
        if (st > L_ - KS_) st = L_ - KS_;
        offr[r] = st - k_base;               // in [0,15]
    }
    float sv[3][4];
    #pragma unroll
    for (int t = 0; t < 3; ++t) {
        int j = t * 16 + l16;                // key col
        #pragma unroll
        for (int r = 0; r < 4; ++r) {
            float x = s[t][r] * 0.125f;      // SCALE = 64^-0.5
            sv[t][r] = (j >= offr[r] && j <= offr[r] + 32) ? x : -1e30f;
        }
    }

    // ---- softmax per row (reduce over 16 lanes of the quad) ----
    float mr[4], sum[4];
    #pragma unroll
    for (int r = 0; r < 4; ++r)
        mr[r] = fmaxf(fmaxf(sv[0][r], sv[1][r]), sv[2][r]);
    #pragma unroll
    for (int o = 1; o < 16; o <<= 1)
        #pragma unroll
        for (int r = 0; r < 4; ++r)
            mr[r] = fmaxf(mr[r], __shfl_xor(mr[r], o, 64));
    #pragma unroll
    for (int t = 0; t < 3; ++t)
        #pragma unroll
        for (int r = 0; r < 4; ++r)
            sv[t][r] = __expf(sv[t][r] - mr[r]);
    #pragma unroll
    for (int r = 0; r < 4; ++r)
        sum[r] = sv[0][r] + sv[1][r] + sv[2][r];
    #pragma unroll
    for (int o = 1; o < 16; o <<= 1)
        #pragma unroll
        for (int r = 0; r < 4; ++r)
            sum[r] += __shfl_xor(sum[r], o, 64);
    #pragma unroll
    for (int r = 0; r < 4; ++r) {
        float inv = 1.0f / sum[r];
        #pragma unroll
        for (int t = 0; t < 3; ++t) sv[t][r] *= inv;
    }

    // ---- P -> LDS (C-layout write, A-layout read) ----
    bf16* P = &Plds[wave][0][0];
    {   // zero pad cols 48..63 (16 rows x 16 cols, 4 elems/lane)
        int rr = lane >> 2;
        int c0 = 48 + (lane & 3) * 4;
        *(bf16x4*)(&P[rr * 72 + c0]) = (bf16x4){(bf16)0.f, (bf16)0.f, (bf16)0.f, (bf16)0.f};
    }
    #pragma unroll
    for (int t = 0; t < 3; ++t)
        #pragma unroll
        for (int r = 0; r < 4; ++r)
            P[(quad * 4 + r) * 72 + t * 16 + l16] = (bf16)sv[t][r];
    __syncthreads();

    bf16x8 pf0 = *(const bf16x8*)(&P[l16 * 72 + quad * 8]);
    bf16x8 pf1 = *(const bf16x8*)(&P[l16 * 72 + 32 + quad * 8]);

    // ---- O = P V : Vt frags (n = d = t*16+l16, k = key) gathered ----
    const bf16* vcol = qkv + (size_t)(b * L_ + k_base) * rs + 2 * DIM_ + h * HDIM_;
    f32x4 o[4] = {};
    #pragma unroll
    for (int t = 0; t < 4; ++t) {
        bf16x8 vf0, vf1;
        #pragma unroll
        for (int j = 0; j < 8; ++j) {
            vf0[j] = vcol[(size_t)(quad * 8 + j) * rs + t * 16 + l16];
            vf1[j] = vcol[(size_t)(32 + quad * 8 + j) * rs + t * 16 + l16];
        }
        o[t] = __builtin_amdgcn_mfma_f32_16x16x32_bf16(pf0, vf0, o[t], 0, 0, 0);
        o[t] = __builtin_amdgcn_mfma_f32_16x16x32_bf16(pf1, vf1, o[t], 0, 0, 0);
    }

    // ---- epilogue: C-layout col = d, row = query ----
    bf16* orow = att + (size_t)(b * L_ + q0) * DIM_ + h * HDIM_;
    #pragma unroll
    for (int t = 0; t < 4; ++t)
        #pragma unroll
        for (int r = 0; r < 4; ++r)
            orow[(size_t)(quad * 4 + r) * DIM_ + t * 16 + l16] = (bf16)o[t][r];
}

extern "C" void kernel_launch(void* const* d_in, const int* in_sizes, int n_in,
                              void* d_out, int out_size, void* d_ws, size_t ws_size,
                              hipStream_t stream) {
    const int n_x  = B_ * L_ * DIM_;       // 4194304
    const int n_wq = 3 * DIM_ * DIM_;      // 786432
    const int n_bq = 3 * DIM_;             // 1536
    const int n_wp = DIM_ * DIM_;          // 262144
    const int n_bp = DIM_;                 // 512

    char* ws = (char*)d_ws;
    bf16* xb  = (bf16*)ws;
    bf16* wqb = xb  + n_x;
    bf16* bqb = wqb + n_wq;
    bf16* wpb = bqb + n_bq;
    bf16* bpb = wpb + n_wp;
    bf16* qkv = bpb + n_bp;                          // 8192 x 1536
    bf16* att = qkv + (size_t)8192 * 1536;           // 8192 x 512

    float* out = (float*)d_out;
    const int M = B_ * L_;  // 8192

    cvt_to_bf16<<<(n_x  + 255) / 256, 256, 0, stream>>>((const float*)d_in[0], xb,  n_x);
    cvt_to_bf16<<<(n_wq + 255) / 256, 256, 0, stream>>>((const float*)d_in[1], wqb, n_wq);
    cvt_to_bf16<<<(n_bq + 255) / 256, 256, 0, stream>>>((const float*)d_in[2], bqb, n_bq);
    cvt_to_bf16<<<(n_wp + 255) / 256, 256, 0, stream>>>((const float*)d_in[3], wpb, n_wp);
    cvt_to_bf16<<<(n_bp + 255) / 256, 256, 0, stream>>>((const float*)d_in[4], bpb, n_bp);

    gemm_nt_bias<bf16><<<dim3(M / 128, (3 * DIM_) / 128), 256, 0, stream>>>(
        xb, wqb, bqb, qkv, M, 3 * DIM_, DIM_);

    na1d_attn_mfma<<<dim3((B_ * HEADS_ * L_) / 64), 256, 0, stream>>>(qkv, att);

    gemm_nt_bias<float><<<dim3(M / 128, DIM_ / 128), 256, 0, stream>>>(
        att, wpb, bpb, out, M, DIM_, DIM_);
}

// Round 5
// 125.729 us; speedup vs baseline: 2.0386x; 1.0770x over previous
//
#include <hip/hip_runtime.h>
#include <hip/hip_bf16.h>

#define B_ 2
#define L_ 4096
#define DIM_ 512
#define HEADS_ 8
#define HDIM_ 64
#define KS_ 33

typedef __bf16 bf16;
typedef __bf16 bf16x4 __attribute__((ext_vector_type(4)));
typedef __bf16 bf16x8 __attribute__((ext_vector_type(8)));
typedef float f32x4 __attribute__((ext_vector_type(4)));

typedef __attribute__((address_space(3))) void lds_void;
typedef __attribute__((address_space(1))) const void glb_void;

__device__ __forceinline__ void async_cp16(const bf16* g, bf16* l)
{
    __builtin_amdgcn_global_load_lds((glb_void*)g, (lds_void*)l, 16, 0, 0);
}

// ---------------------------------------------------------------------------
// Single fused fp32->bf16 convert for all 5 inputs (sizes are compile-time).
// 2048 elems per block, 8 per thread. All sizes divisible by 8.
// ---------------------------------------------------------------------------
__global__ __launch_bounds__(256)
void cvt_all(const float* __restrict__ x,  const float* __restrict__ wq,
             const float* __restrict__ bq, const float* __restrict__ wp,
             const float* __restrict__ bp,
             bf16* __restrict__ xb,  bf16* __restrict__ wqb,
             bf16* __restrict__ bqb, bf16* __restrict__ wpb,
             bf16* __restrict__ bpb)
{
    const int blk = blockIdx.x;
    const float* src; bf16* dst; int n, base;
    if (blk < 2048)       { src = x;  dst = xb;  n = 4194304; base = blk; }
    else if (blk < 2432)  { src = wq; dst = wqb; n = 786432;  base = blk - 2048; }
    else if (blk < 2560)  { src = wp; dst = wpb; n = 262144;  base = blk - 2432; }
    else if (blk == 2560) { src = bq; dst = bqb; n = 1536;    base = 0; }
    else                  { src = bp; dst = bpb; n = 512;     base = 0; }
    int i = base * 2048 + threadIdx.x * 8;
    if (i + 8 <= n) {
        float4 a = *(const float4*)(src + i);
        float4 b = *(const float4*)(src + i + 4);
        bf16x8 o;
        o[0] = (bf16)a.x; o[1] = (bf16)a.y; o[2] = (bf16)a.z; o[3] = (bf16)a.w;
        o[4] = (bf16)b.x; o[5] = (bf16)b.y; o[6] = (bf16)b.z; o[7] = (bf16)b.w;
        *(bf16x8*)(dst + i) = o;
    }
}

// ---------------------------------------------------------------------------
// C[M,N] = A[M,K] * W[N,K]^T + bias[N]; bf16 in, OutT out, fp32 accumulate.
// Block = 256 threads (4 waves, 2x2), tile 128x128, BK=64.
// Staging via global_load_lds width=16 (m97 ladder step). LDS is unpadded
// [128][64] with XOR swizzle: logical chunk (r, c8) stored at column
// c8 ^ (r&7). Staging lane's LDS slot is fixed (base + lane*16); it loads
// the matching logical chunk from global. Fragment reads then hit all 32
// banks at 2-way aliasing (free, m136).
// ---------------------------------------------------------------------------
template <typename OutT>
__global__ __launch_bounds__(256)
void gemm_nt_bias(const bf16* __restrict__ A, const bf16* __restrict__ W,
                  const bf16* __restrict__ bias, OutT* __restrict__ C,
                  int M, int N, int K)
{
    __shared__ bf16 As[128][64];
    __shared__ bf16 Bs[128][64];

    const int tid  = threadIdx.x;
    const int wave = tid >> 6;
    const int lane = tid & 63;
    const int wm   = (wave >> 1) * 64;
    const int wn   = (wave & 1) * 64;
    const int l16  = lane & 15;
    const int quad = lane >> 4;

    const int row0 = blockIdx.x * 128;
    const int col0 = blockIdx.y * 128;

    f32x4 acc[4][4] = {};

    for (int k0 = 0; k0 < K; k0 += 64) {
        #pragma unroll
        for (int it = 0; it < 4; ++it) {
            int f   = it * 256 + tid;          // physical 16B chunk 0..1023
            int r   = f >> 3;                  // tile row
            int c8l = (f & 7) ^ (r & 7);       // logical chunk within row
            async_cp16(&A[(size_t)(row0 + r) * K + k0 + c8l * 8], &As[r][(f & 7) * 8]);
            async_cp16(&W[(size_t)(col0 + r) * K + k0 + c8l * 8], &Bs[r][(f & 7) * 8]);
        }
        __syncthreads();

        #pragma unroll
        for (int ks = 0; ks < 2; ++ks) {
            bf16x8 af[4], bfr[4];
            #pragma unroll
            for (int i = 0; i < 4; ++i) {
                int ra = wm + i * 16 + l16;
                int rb = wn + i * 16 + l16;
                af[i]  = *(const bf16x8*)(&As[ra][((ks * 4 + quad) ^ (ra & 7)) * 8]);
                bfr[i] = *(const bf16x8*)(&Bs[rb][((ks * 4 + quad) ^ (rb & 7)) * 8]);
            }
            #pragma unroll
            for (int mi = 0; mi < 4; ++mi)
                #pragma unroll
                for (int ni = 0; ni < 4; ++ni)
                    acc[mi][ni] = __builtin_amdgcn_mfma_f32_16x16x32_bf16(
                        af[mi], bfr[ni], acc[mi][ni], 0, 0, 0);
        }
        __syncthreads();
    }

    // C/D layout: col = lane&15, row = quad*4 + reg (m89/m91-verified)
    #pragma unroll
    for (int ni = 0; ni < 4; ++ni) {
        int n = col0 + wn + ni * 16 + l16;
        float bv = (float)bias[n];
        #pragma unroll
        for (int mi = 0; mi < 4; ++mi) {
            int mrow = row0 + wm + mi * 16 + quad * 4;
            #pragma unroll
            for (int r = 0; r < 4; ++r)
                C[(size_t)(mrow + r) * N + n] = (OutT)(acc[mi][ni][r] + bv);
        }
    }
}

// ---------------------------------------------------------------------------
// MFMA neighborhood attention (passing R4 kernel, unchanged).
// One wave per 16 consecutive queries of one (b,h); 48-key window union.
// ---------------------------------------------------------------------------
__global__ __launch_bounds__(256)
void na1d_attn_mfma(const bf16* __restrict__ qkv, bf16* __restrict__ att)
{
    __shared__ bf16 Plds[4][16][72];

    const int wave = threadIdx.x >> 6;
    const int lane = threadIdx.x & 63;
    const int l16  = lane & 15;
    const int quad = lane >> 4;

    const int wid = blockIdx.x * 4 + wave;   // 0..4095
    const int qg  = wid & 255;
    const int bh  = wid >> 8;
    const int h   = bh & 7;
    const int b   = bh >> 3;
    const int q0  = qg * 16;

    int k_base = q0 - 16;
    if (k_base < 0) k_base = 0;
    if (k_base > L_ - KS_) k_base = L_ - KS_;

    const size_t rs = 3 * DIM_;  // 1536

    const bf16* qptr = qkv + (size_t)(b * L_ + q0 + l16) * rs + h * HDIM_ + quad * 8;
    bf16x8 qf0 = *(const bf16x8*)(qptr);
    bf16x8 qf1 = *(const bf16x8*)(qptr + 32);

    const bf16* kcol = qkv + (size_t)(b * L_ + k_base) * rs + DIM_ + h * HDIM_;
    f32x4 s[3] = {};
    #pragma unroll
    for (int t = 0; t < 3; ++t) {
        const bf16* kptr = kcol + (size_t)(t * 16 + l16) * rs + quad * 8;
        bf16x8 kf0 = *(const bf16x8*)(kptr);
        bf16x8 kf1 = *(const bf16x8*)(kptr + 32);
        s[t] = __builtin_amdgcn_mfma_f32_16x16x32_bf16(qf0, kf0, s[t], 0, 0, 0);
        s[t] = __builtin_amdgcn_mfma_f32_16x16x32_bf16(qf1, kf1, s[t], 0, 0, 0);
    }

    int offr[4];
    #pragma unroll
    for (int r = 0; r < 4; ++r) {
        int lq = q0 + quad * 4 + r;
        int st = lq - KS_ / 2;
        if (st < 0) st = 0;
        if (st > L_ - KS_) st = L_ - KS_;
        offr[r] = st - k_base;               // in [0,15]
    }
    float sv[3][4];
    #pragma unroll
    for (int t = 0; t < 3; ++t) {
        int j = t * 16 + l16;
        #pragma unroll
        for (int r = 0; r < 4; ++r) {
            float x = s[t][r] * 0.125f;
            sv[t][r] = (j >= offr[r] && j <= offr[r] + 32) ? x : -1e30f;
        }
    }

    float mr[4], sum[4];
    #pragma unroll
    for (int r = 0; r < 4; ++r)
        mr[r] = fmaxf(fmaxf(sv[0][r], sv[1][r]), sv[2][r]);
    #pragma unroll
    for (int o = 1; o < 16; o <<= 1)
        #pragma unroll
        for (int r = 0; r < 4; ++r)
            mr[r] = fmaxf(mr[r], __shfl_xor(mr[r], o, 64));
    #pragma unroll
    for (int t = 0; t < 3; ++t)
        #pragma unroll
        for (int r = 0; r < 4; ++r)
            sv[t][r] = __expf(sv[t][r] - mr[r]);
    #pragma unroll
    for (int r = 0; r < 4; ++r)
        sum[r] = sv[0][r] + sv[1][r] + sv[2][r];
    #pragma unroll
    for (int o = 1; o < 16; o <<= 1)
        #pragma unroll
        for (int r = 0; r < 4; ++r)
            sum[r] += __shfl_xor(sum[r], o, 64);
    #pragma unroll
    for (int r = 0; r < 4; ++r) {
        float inv = 1.0f / sum[r];
        #pragma unroll
        for (int t = 0; t < 3; ++t) sv[t][r] *= inv;
    }

    bf16* P = &Plds[wave][0][0];
    {
        int rr = lane >> 2;
        int c0 = 48 + (lane & 3) * 4;
        *(bf16x4*)(&P[rr * 72 + c0]) = (bf16x4){(bf16)0.f, (bf16)0.f, (bf16)0.f, (bf16)0.f};
    }
    #pragma unroll
    for (int t = 0; t < 3; ++t)
        #pragma unroll
        for (int r = 0; r < 4; ++r)
            P[(quad * 4 + r) * 72 + t * 16 + l16] = (bf16)sv[t][r];
    __syncthreads();

    bf16x8 pf0 = *(const bf16x8*)(&P[l16 * 72 + quad * 8]);
    bf16x8 pf1 = *(const bf16x8*)(&P[l16 * 72 + 32 + quad * 8]);

    const bf16* vcol = qkv + (size_t)(b * L_ + k_base) * rs + 2 * DIM_ + h * HDIM_;
    f32x4 o[4] = {};
    #pragma unroll
    for (int t = 0; t < 4; ++t) {
        bf16x8 vf0, vf1;
        #pragma unroll
        for (int j = 0; j < 8; ++j) {
            vf0[j] = vcol[(size_t)(quad * 8 + j) * rs + t * 16 + l16];
            vf1[j] = vcol[(size_t)(32 + quad * 8 + j) * rs + t * 16 + l16];
        }
        o[t] = __builtin_amdgcn_mfma_f32_16x16x32_bf16(pf0, vf0, o[t], 0, 0, 0);
        o[t] = __builtin_amdgcn_mfma_f32_16x16x32_bf16(pf1, vf1, o[t], 0, 0, 0);
    }

    bf16* orow = att + (size_t)(b * L_ + q0) * DIM_ + h * HDIM_;
    #pragma unroll
    for (int t = 0; t < 4; ++t)
        #pragma unroll
        for (int r = 0; r < 4; ++r)
            orow[(size_t)(quad * 4 + r) * DIM_ + t * 16 + l16] = (bf16)o[t][r];
}

extern "C" void kernel_launch(void* const* d_in, const int* in_sizes, int n_in,
                              void* d_out, int out_size, void* d_ws, size_t ws_size,
                              hipStream_t stream) {
    const int n_x  = B_ * L_ * DIM_;       // 4194304
    const int n_wq = 3 * DIM_ * DIM_;      // 786432
    const int n_bq = 3 * DIM_;             // 1536
    const int n_wp = DIM_ * DIM_;          // 262144
    const int n_bp = DIM_;                 // 512

    char* ws = (char*)d_ws;
    bf16* xb  = (bf16*)ws;
    bf16* wqb = xb  + n_x;
    bf16* bqb = wqb + n_wq;
    bf16* wpb = bqb + n_bq;
    bf16* bpb = wpb + n_wp;
    bf16* qkv = bpb + n_bp;                          // 8192 x 1536
    bf16* att = qkv + (size_t)8192 * 1536;           // 8192 x 512

    float* out = (float*)d_out;
    const int M = B_ * L_;  // 8192

    cvt_all<<<2562, 256, 0, stream>>>(
        (const float*)d_in[0], (const float*)d_in[1], (const float*)d_in[2],
        (const float*)d_in[3], (const float*)d_in[4],
        xb, wqb, bqb, wpb, bpb);

    gemm_nt_bias<bf16><<<dim3(M / 128, (3 * DIM_) / 128), 256, 0, stream>>>(
        xb, wqb, bqb, qkv, M, 3 * DIM_, DIM_);

    na1d_attn_mfma<<<dim3((B_ * HEADS_ * L_) / 64), 256, 0, stream>>>(qkv, att);

    gemm_nt_bias<float><<<dim3(M / 128, DIM_ / 128), 256, 0, stream>>>(
        att, wpb, bpb, out, M, DIM_, DIM_);
}

// Round 6
// 125.613 us; speedup vs baseline: 2.0404x; 1.0009x over previous
//
#include <hip/hip_runtime.h>
#include <hip/hip_bf16.h>

#define B_ 2
#define L_ 4096
#define DIM_ 512
#define HEADS_ 8
#define HDIM_ 64
#define KS_ 33

typedef __bf16 bf16;
typedef __bf16 bf16x4 __attribute__((ext_vector_type(4)));
typedef __bf16 bf16x8 __attribute__((ext_vector_type(8)));
typedef float f32x4 __attribute__((ext_vector_type(4)));

typedef __attribute__((address_space(3))) void lds_void;
typedef __attribute__((address_space(1))) const void glb_void;

__device__ __forceinline__ void async_cp16(const bf16* g, bf16* l)
{
    __builtin_amdgcn_global_load_lds((glb_void*)g, (lds_void*)l, 16, 0, 0);
}

// ---------------------------------------------------------------------------
// Single fused fp32->bf16 convert for all 5 inputs (sizes are compile-time).
// ---------------------------------------------------------------------------
__global__ __launch_bounds__(256)
void cvt_all(const float* __restrict__ x,  const float* __restrict__ wq,
             const float* __restrict__ bq, const float* __restrict__ wp,
             const float* __restrict__ bp,
             bf16* __restrict__ xb,  bf16* __restrict__ wqb,
             bf16* __restrict__ bqb, bf16* __restrict__ wpb,
             bf16* __restrict__ bpb)
{
    const int blk = blockIdx.x;
    const float* src; bf16* dst; int n, base;
    if (blk < 2048)       { src = x;  dst = xb;  n = 4194304; base = blk; }
    else if (blk < 2432)  { src = wq; dst = wqb; n = 786432;  base = blk - 2048; }
    else if (blk < 2560)  { src = wp; dst = wpb; n = 262144;  base = blk - 2432; }
    else if (blk == 2560) { src = bq; dst = bqb; n = 1536;    base = 0; }
    else                  { src = bp; dst = bpb; n = 512;     base = 0; }
    int i = base * 2048 + threadIdx.x * 8;
    if (i + 8 <= n) {
        float4 a = *(const float4*)(src + i);
        float4 b = *(const float4*)(src + i + 4);
        bf16x8 o;
        o[0] = (bf16)a.x; o[1] = (bf16)a.y; o[2] = (bf16)a.z; o[3] = (bf16)a.w;
        o[4] = (bf16)b.x; o[5] = (bf16)b.y; o[6] = (bf16)b.z; o[7] = (bf16)b.w;
        *(bf16x8*)(dst + i) = o;
    }
}

// ---------------------------------------------------------------------------
// C[M,N] = A[M,K] * W[N,K]^T + bias[N]; bf16 in, OutT out, fp32 accumulate.
// Block = 256 threads (4 waves, 2x2), tile 128x128, BK=64.
// global_load_lds width=16 staging; unpadded LDS + XOR swizzle (R5, passing).
// M-tile -> XCD mapping is already L2-local (gridDim.x = 64 divisible by 8).
// ---------------------------------------------------------------------------
template <typename OutT>
__global__ __launch_bounds__(256)
void gemm_nt_bias(const bf16* __restrict__ A, const bf16* __restrict__ W,
                  const bf16* __restrict__ bias, OutT* __restrict__ C,
                  int M, int N, int K)
{
    __shared__ bf16 As[128][64];
    __shared__ bf16 Bs[128][64];

    const int tid  = threadIdx.x;
    const int wave = tid >> 6;
    const int lane = tid & 63;
    const int wm   = (wave >> 1) * 64;
    const int wn   = (wave & 1) * 64;
    const int l16  = lane & 15;
    const int quad = lane >> 4;

    const int row0 = blockIdx.x * 128;
    const int col0 = blockIdx.y * 128;

    f32x4 acc[4][4] = {};

    for (int k0 = 0; k0 < K; k0 += 64) {
        #pragma unroll
        for (int it = 0; it < 4; ++it) {
            int f   = it * 256 + tid;          // physical 16B chunk 0..1023
            int r   = f >> 3;                  // tile row
            int c8l = (f & 7) ^ (r & 7);       // logical chunk within row
            async_cp16(&A[(size_t)(row0 + r) * K + k0 + c8l * 8], &As[r][(f & 7) * 8]);
            async_cp16(&W[(size_t)(col0 + r) * K + k0 + c8l * 8], &Bs[r][(f & 7) * 8]);
        }
        __syncthreads();

        #pragma unroll
        for (int ks = 0; ks < 2; ++ks) {
            bf16x8 af[4], bfr[4];
            #pragma unroll
            for (int i = 0; i < 4; ++i) {
                int ra = wm + i * 16 + l16;
                int rb = wn + i * 16 + l16;
                af[i]  = *(const bf16x8*)(&As[ra][((ks * 4 + quad) ^ (ra & 7)) * 8]);
                bfr[i] = *(const bf16x8*)(&Bs[rb][((ks * 4 + quad) ^ (rb & 7)) * 8]);
            }
            #pragma unroll
            for (int mi = 0; mi < 4; ++mi)
                #pragma unroll
                for (int ni = 0; ni < 4; ++ni)
                    acc[mi][ni] = __builtin_amdgcn_mfma_f32_16x16x32_bf16(
                        af[mi], bfr[ni], acc[mi][ni], 0, 0, 0);
        }
        __syncthreads();
    }

    #pragma unroll
    for (int ni = 0; ni < 4; ++ni) {
        int n = col0 + wn + ni * 16 + l16;
        float bv = (float)bias[n];
        #pragma unroll
        for (int mi = 0; mi < 4; ++mi) {
            int mrow = row0 + wm + mi * 16 + quad * 4;
            #pragma unroll
            for (int r = 0; r < 4; ++r)
                C[(size_t)(mrow + r) * N + n] = (OutT)(acc[mi][ni][r] + bv);
        }
    }
}

// ---------------------------------------------------------------------------
// MFMA neighborhood attention (R4/R5 passing kernel) + XCD-aware swizzle.
// HW dispatches blocks round-robin across 8 XCDs (hw XCD = blk % 8). Swizzle
// logical = (blk&7)*128 + (blk>>3) so XCD x owns logical blocks
// [128x, 128x+128) = exactly 2 complete (b,h) slices -> per-XCD K+V working
// set = 2 MB < 4 MB L2 (vs ~25 MB without swizzle). Perf heuristic only;
// any hw mapping change affects speed, not correctness.
// ---------------------------------------------------------------------------
__global__ __launch_bounds__(256)
void na1d_attn_mfma(const bf16* __restrict__ qkv, bf16* __restrict__ att)
{
    __shared__ bf16 Plds[4][16][72];

    const int wave = threadIdx.x >> 6;
    const int lane = threadIdx.x & 63;
    const int l16  = lane & 15;
    const int quad = lane >> 4;

    const int lblk = (blockIdx.x & 7) * 128 + (blockIdx.x >> 3);  // XCD swizzle
    const int wid = lblk * 4 + wave;         // 0..4095
    const int qg  = wid & 255;
    const int bh  = wid >> 8;
    const int h   = bh & 7;
    const int b   = bh >> 3;
    const int q0  = qg * 16;

    int k_base = q0 - 16;
    if (k_base < 0) k_base = 0;
    if (k_base > L_ - KS_) k_base = L_ - KS_;

    const size_t rs = 3 * DIM_;  // 1536

    const bf16* qptr = qkv + (size_t)(b * L_ + q0 + l16) * rs + h * HDIM_ + quad * 8;
    bf16x8 qf0 = *(const bf16x8*)(qptr);
    bf16x8 qf1 = *(const bf16x8*)(qptr + 32);

    const bf16* kcol = qkv + (size_t)(b * L_ + k_base) * rs + DIM_ + h * HDIM_;
    f32x4 s[3] = {};
    #pragma unroll
    for (int t = 0; t < 3; ++t) {
        const bf16* kptr = kcol + (size_t)(t * 16 + l16) * rs + quad * 8;
        bf16x8 kf0 = *(const bf16x8*)(kptr);
        bf16x8 kf1 = *(const bf16x8*)(kptr + 32);
        s[t] = __builtin_amdgcn_mfma_f32_16x16x32_bf16(qf0, kf0, s[t], 0, 0, 0);
        s[t] = __builtin_amdgcn_mfma_f32_16x16x32_bf16(qf1, kf1, s[t], 0, 0, 0);
    }

    int offr[4];
    #pragma unroll
    for (int r = 0; r < 4; ++r) {
        int lq = q0 + quad * 4 + r;
        int st = lq - KS_ / 2;
        if (st < 0) st = 0;
        if (st > L_ - KS_) st = L_ - KS_;
        offr[r] = st - k_base;               // in [0,15]
    }
    float sv[3][4];
    #pragma unroll
    for (int t = 0; t < 3; ++t) {
        int j = t * 16 + l16;
        #pragma unroll
        for (int r = 0; r < 4; ++r) {
            float x = s[t][r] * 0.125f;
            sv[t][r] = (j >= offr[r] && j <= offr[r] + 32) ? x : -1e30f;
        }
    }

    float mr[4], sum[4];
    #pragma unroll
    for (int r = 0; r < 4; ++r)
        mr[r] = fmaxf(fmaxf(sv[0][r], sv[1][r]), sv[2][r]);
    #pragma unroll
    for (int o = 1; o < 16; o <<= 1)
        #pragma unroll
        for (int r = 0; r < 4; ++r)
            mr[r] = fmaxf(mr[r], __shfl_xor(mr[r], o, 64));
    #pragma unroll
    for (int t = 0; t < 3; ++t)
        #pragma unroll
        for (int r = 0; r < 4; ++r)
            sv[t][r] = __expf(sv[t][r] - mr[r]);
    #pragma unroll
    for (int r = 0; r < 4; ++r)
        sum[r] = sv[0][r] + sv[1][r] + sv[2][r];
    #pragma unroll
    for (int o = 1; o < 16; o <<= 1)
        #pragma unroll
        for (int r = 0; r < 4; ++r)
            sum[r] += __shfl_xor(sum[r], o, 64);
    #pragma unroll
    for (int r = 0; r < 4; ++r) {
        float inv = 1.0f / sum[r];
        #pragma unroll
        for (int t = 0; t < 3; ++t) sv[t][r] *= inv;
    }

    bf16* P = &Plds[wave][0][0];
    {
        int rr = lane >> 2;
        int c0 = 48 + (lane & 3) * 4;
        *(bf16x4*)(&P[rr * 72 + c0]) = (bf16x4){(bf16)0.f, (bf16)0.f, (bf16)0.f, (bf16)0.f};
    }
    #pragma unroll
    for (int t = 0; t < 3; ++t)
        #pragma unroll
        for (int r = 0; r < 4; ++r)
            P[(quad * 4 + r) * 72 + t * 16 + l16] = (bf16)sv[t][r];
    __syncthreads();

    bf16x8 pf0 = *(const bf16x8*)(&P[l16 * 72 + quad * 8]);
    bf16x8 pf1 = *(const bf16x8*)(&P[l16 * 72 + 32 + quad * 8]);

    const bf16* vcol = qkv + (size_t)(b * L_ + k_base) * rs + 2 * DIM_ + h * HDIM_;
    f32x4 o[4] = {};
    #pragma unroll
    for (int t = 0; t < 4; ++t) {
        bf16x8 vf0, vf1;
        #pragma unroll
        for (int j = 0; j < 8; ++j) {
            vf0[j] = vcol[(size_t)(quad * 8 + j) * rs + t * 16 + l16];
            vf1[j] = vcol[(size_t)(32 + quad * 8 + j) * rs + t * 16 + l16];
        }
        o[t] = __builtin_amdgcn_mfma_f32_16x16x32_bf16(pf0, vf0, o[t], 0, 0, 0);
        o[t] = __builtin_amdgcn_mfma_f32_16x16x32_bf16(pf1, vf1, o[t], 0, 0, 0);
    }

    bf16* orow = att + (size_t)(b * L_ + q0) * DIM_ + h * HDIM_;
    #pragma unroll
    for (int t = 0; t < 4; ++t)
        #pragma unroll
        for (int r = 0; r < 4; ++r)
            orow[(size_t)(quad * 4 + r) * DIM_ + t * 16 + l16] = (bf16)o[t][r];
}

extern "C" void kernel_launch(void* const* d_in, const int* in_sizes, int n_in,
                              void* d_out, int out_size, void* d_ws, size_t ws_size,
                              hipStream_t stream) {
    const int n_x  = B_ * L_ * DIM_;       // 4194304
    const int n_wq = 3 * DIM_ * DIM_;      // 786432
    const int n_bq = 3 * DIM_;             // 1536
    const int n_wp = DIM_ * DIM_;          // 262144
    const int n_bp = DIM_;                 // 512

    char* ws = (char*)d_ws;
    bf16* xb  = (bf16*)ws;
    bf16* wqb = xb  + n_x;
    bf16* bqb = wqb + n_wq;
    bf16* wpb = bqb + n_bq;
    bf16* bpb = wpb + n_wp;
    bf16* qkv = bpb + n_bp;                          // 8192 x 1536
    bf16* att = qkv + (size_t)8192 * 1536;           // 8192 x 512

    float* out = (float*)d_out;
    const int M = B_ * L_;  // 8192

    cvt_all<<<2562, 256, 0, stream>>>(
        (const float*)d_in[0], (const float*)d_in[1], (const float*)d_in[2],
        (const float*)d_in[3], (const float*)d_in[4],
        xb, wqb, bqb, wpb, bpb);

    gemm_nt_bias<bf16><<<dim3(M / 128, (3 * DIM_) / 128), 256, 0, stream>>>(
        xb, wqb, bqb, qkv, M, 3 * DIM_, DIM_);

    na1d_attn_mfma<<<dim3((B_ * HEADS_ * L_) / 64), 256, 0, stream>>>(qkv, att);

    gemm_nt_bias<float><<<dim3(M / 128, DIM_ / 128), 256, 0, stream>>>(
        att, wpb, bpb, out, M, DIM_, DIM_);
}

// Round 7
// 123.169 us; speedup vs baseline: 2.0809x; 1.0198x over previous
//
#include <hip/hip_runtime.h>
#include <hip/hip_bf16.h>

#define B_ 2
#define L_ 4096
#define DIM_ 512
#define HEADS_ 8
#define HDIM_ 64
#define KS_ 33

typedef __bf16 bf16;
typedef __bf16 bf16x4 __attribute__((ext_vector_type(4)));
typedef __bf16 bf16x8 __attribute__((ext_vector_type(8)));
typedef float f32x4 __attribute__((ext_vector_type(4)));

typedef __attribute__((address_space(3))) void lds_void;
typedef __attribute__((address_space(1))) const void glb_void;

__device__ __forceinline__ void async_cp16(const bf16* g, bf16* l)
{
    __builtin_amdgcn_global_load_lds((glb_void*)g, (lds_void*)l, 16, 0, 0);
}

// ---------------------------------------------------------------------------
// Single fused fp32->bf16 convert for all 5 inputs (R5, passing, unchanged).
// ---------------------------------------------------------------------------
__global__ __launch_bounds__(256)
void cvt_all(const float* __restrict__ x,  const float* __restrict__ wq,
             const float* __restrict__ bq, const float* __restrict__ wp,
             const float* __restrict__ bp,
             bf16* __restrict__ xb,  bf16* __restrict__ wqb,
             bf16* __restrict__ bqb, bf16* __restrict__ wpb,
             bf16* __restrict__ bpb)
{
    const int blk = blockIdx.x;
    const float* src; bf16* dst; int n, base;
    if (blk < 2048)       { src = x;  dst = xb;  n = 4194304; base = blk; }
    else if (blk < 2432)  { src = wq; dst = wqb; n = 786432;  base = blk - 2048; }
    else if (blk < 2560)  { src = wp; dst = wpb; n = 262144;  base = blk - 2432; }
    else if (blk == 2560) { src = bq; dst = bqb; n = 1536;    base = 0; }
    else                  { src = bp; dst = bpb; n = 512;     base = 0; }
    int i = base * 2048 + threadIdx.x * 8;
    if (i + 8 <= n) {
        float4 a = *(const float4*)(src + i);
        float4 b = *(const float4*)(src + i + 4);
        bf16x8 o;
        o[0] = (bf16)a.x; o[1] = (bf16)a.y; o[2] = (bf16)a.z; o[3] = (bf16)a.w;
        o[4] = (bf16)b.x; o[5] = (bf16)b.y; o[6] = (bf16)b.z; o[7] = (bf16)b.w;
        *(bf16x8*)(dst + i) = o;
    }
}

// ---------------------------------------------------------------------------
// C[M,N] = A[M,K] * W[N,K]^T + bias[N] (R5, passing, unchanged).
// ---------------------------------------------------------------------------
template <typename OutT>
__global__ __launch_bounds__(256)
void gemm_nt_bias(const bf16* __restrict__ A, const bf16* __restrict__ W,
                  const bf16* __restrict__ bias, OutT* __restrict__ C,
                  int M, int N, int K)
{
    __shared__ bf16 As[128][64];
    __shared__ bf16 Bs[128][64];

    const int tid  = threadIdx.x;
    const int wave = tid >> 6;
    const int lane = tid & 63;
    const int wm   = (wave >> 1) * 64;
    const int wn   = (wave & 1) * 64;
    const int l16  = lane & 15;
    const int quad = lane >> 4;

    const int row0 = blockIdx.x * 128;
    const int col0 = blockIdx.y * 128;

    f32x4 acc[4][4] = {};

    for (int k0 = 0; k0 < K; k0 += 64) {
        #pragma unroll
        for (int it = 0; it < 4; ++it) {
            int f   = it * 256 + tid;
            int r   = f >> 3;
            int c8l = (f & 7) ^ (r & 7);
            async_cp16(&A[(size_t)(row0 + r) * K + k0 + c8l * 8], &As[r][(f & 7) * 8]);
            async_cp16(&W[(size_t)(col0 + r) * K + k0 + c8l * 8], &Bs[r][(f & 7) * 8]);
        }
        __syncthreads();

        #pragma unroll
        for (int ks = 0; ks < 2; ++ks) {
            bf16x8 af[4], bfr[4];
            #pragma unroll
            for (int i = 0; i < 4; ++i) {
                int ra = wm + i * 16 + l16;
                int rb = wn + i * 16 + l16;
                af[i]  = *(const bf16x8*)(&As[ra][((ks * 4 + quad) ^ (ra & 7)) * 8]);
                bfr[i] = *(const bf16x8*)(&Bs[rb][((ks * 4 + quad) ^ (rb & 7)) * 8]);
            }
            #pragma unroll
            for (int mi = 0; mi < 4; ++mi)
                #pragma unroll
                for (int ni = 0; ni < 4; ++ni)
                    acc[mi][ni] = __builtin_amdgcn_mfma_f32_16x16x32_bf16(
                        af[mi], bfr[ni], acc[mi][ni], 0, 0, 0);
        }
        __syncthreads();
    }

    #pragma unroll
    for (int ni = 0; ni < 4; ++ni) {
        int n = col0 + wn + ni * 16 + l16;
        float bv = (float)bias[n];
        #pragma unroll
        for (int mi = 0; mi < 4; ++mi) {
            int mrow = row0 + wm + mi * 16 + quad * 4;
            #pragma unroll
            for (int r = 0; r < 4; ++r)
                C[(size_t)(mrow + r) * N + n] = (OutT)(acc[mi][ni][r] + bv);
        }
    }
}

// ---------------------------------------------------------------------------
// MFMA neighborhood attention, LDS-staged K/V version.
// One block = 64 consecutive queries of one (b,h); 4 waves x 16 queries.
// Block stages qkv rows [Q0-16, Q0+80) (clamped to [0,L), masked where
// wrong): K via global_load_lds into XOR-swizzled [96][64]; V via vector
// load + b32 ds_write into stride-66 rows (quad rows -> distinct banks for
// the scalar transposed reads). Per-wave k_base = clamp(q0w-16, 0, L-48):
// every clamp bound is a multiple of 16, so rel = k_base-(Q0-16) is 16-
// aligned and K-fragment LDS rows keep the GEMM-proven XOR bank pattern.
// Block->XCD decode places each block on the XCD whose L2 holds the qkv
// row panel gemm1 just wrote (writer XCD = panel%8). Heuristic only.
// ---------------------------------------------------------------------------
__global__ __launch_bounds__(256)
void na1d_attn_mfma(const bf16* __restrict__ qkv, bf16* __restrict__ att)
{
    __shared__ bf16 Klds[96 * 64];        // flat chunks: (row*8+pc)*8 elems
    __shared__ bf16 Vlds[96 * 66];        // [row][66] padded rows
    __shared__ bf16 Plds[4][16][72];

    const int tid  = threadIdx.x;
    const int wave = tid >> 6;
    const int lane = tid & 63;
    const int l16  = lane & 15;
    const int quad = lane >> 4;

    // XCD-aligned decode: panel p = 8*jj + (blk&7) runs on XCD (blk&7),
    // matching gemm1's writer XCD for that row panel.
    const int xcd  = blockIdx.x & 7;
    const int s    = blockIdx.x >> 3;
    const int jj   = s & 3;
    const int half = (s >> 2) & 1;
    const int h    = (s >> 3) & 7;
    const int b    = s >> 6;
    const int p    = jj * 8 + xcd;        // row panel 0..31
    const int Q0   = p * 128 + half * 64; // block query base

    const size_t rs = 3 * DIM_;           // 1536
    const size_t rowbase = (size_t)b * L_;

    // ---- stage K: 96 rows x 8 chunks = 768 global_load_lds ----
    #pragma unroll
    for (int i = 0; i < 3; ++i) {
        int ck = i * 256 + tid;           // chunk id
        int r  = ck >> 3;
        int pc = ck & 7;
        int lc = pc ^ (r & 7);            // logical chunk (XOR swizzle)
        int g  = Q0 - 16 + r;
        g = g < 0 ? 0 : (g > L_ - 1 ? L_ - 1 : g);
        async_cp16(qkv + (rowbase + g) * rs + DIM_ + h * HDIM_ + lc * 8,
                   Klds + (size_t)ck * 8);
    }
    // ---- stage V: vector load + 4x b32 ds_write into stride-66 rows ----
    {
        unsigned int* V32 = (unsigned int*)Vlds;
        #pragma unroll
        for (int i = 0; i < 3; ++i) {
            int cv = i * 256 + tid;
            int r  = cv >> 3;
            int pc = cv & 7;
            int g  = Q0 - 16 + r;
            g = g < 0 ? 0 : (g > L_ - 1 ? L_ - 1 : g);
            uint4 val = *(const uint4*)(qkv + (rowbase + g) * rs + 2 * DIM_ + h * HDIM_ + pc * 8);
            int base = r * 33 + pc * 4;   // uint index; row stride 33 uints
            V32[base + 0] = val.x; V32[base + 1] = val.y;
            V32[base + 2] = val.z; V32[base + 3] = val.w;
        }
    }

    // ---- Q fragments (direct from global) ----
    const int q0w = Q0 + wave * 16;
    const bf16* qptr = qkv + (rowbase + q0w + l16) * rs + h * HDIM_ + quad * 8;
    bf16x8 qf0 = *(const bf16x8*)(qptr);
    bf16x8 qf1 = *(const bf16x8*)(qptr + 32);

    int k_base = q0w - 16;
    if (k_base > L_ - 48) k_base = L_ - 48;
    if (k_base < 0) k_base = 0;
    const int rel = k_base - (Q0 - 16);   // multiple of 16, in [0, 48]

    __syncthreads();                      // drains global_load_lds + ds_writes

    // ---- S = Q K^T over 3 key tiles (K from LDS) ----
    f32x4 sacc[3] = {};
    #pragma unroll
    for (int t = 0; t < 3; ++t) {
        int r = rel + t * 16 + l16;
        bf16x8 kf0 = *(const bf16x8*)(Klds + r * 64 + ((quad ^ (r & 7)) * 8));
        bf16x8 kf1 = *(const bf16x8*)(Klds + r * 64 + (((4 + quad) ^ (r & 7)) * 8));
        sacc[t] = __builtin_amdgcn_mfma_f32_16x16x32_bf16(qf0, kf0, sacc[t], 0, 0, 0);
        sacc[t] = __builtin_amdgcn_mfma_f32_16x16x32_bf16(qf1, kf1, sacc[t], 0, 0, 0);
    }

    // ---- mask + scale (offr in [0,15]) ----
    int offr[4];
    #pragma unroll
    for (int r = 0; r < 4; ++r) {
        int lq = q0w + quad * 4 + r;
        int st = lq - KS_ / 2;
        if (st < 0) st = 0;
        if (st > L_ - KS_) st = L_ - KS_;
        offr[r] = st - k_base;
    }
    float sv[3][4];
    #pragma unroll
    for (int t = 0; t < 3; ++t) {
        int j = t * 16 + l16;
        #pragma unroll
        for (int r = 0; r < 4; ++r) {
            float xv = sacc[t][r] * 0.125f;   // SCALE = 64^-0.5
            sv[t][r] = (j >= offr[r] && j <= offr[r] + 32) ? xv : -1e30f;
        }
    }

    // ---- softmax per row (quad-local butterfly over 16 lanes) ----
    float mr[4], sum[4];
    #pragma unroll
    for (int r = 0; r < 4; ++r)
        mr[r] = fmaxf(fmaxf(sv[0][r], sv[1][r]), sv[2][r]);
    #pragma unroll
    for (int o = 1; o < 16; o <<= 1)
        #pragma unroll
        for (int r = 0; r < 4; ++r)
            mr[r] = fmaxf(mr[r], __shfl_xor(mr[r], o, 64));
    #pragma unroll
    for (int t = 0; t < 3; ++t)
        #pragma unroll
        for (int r = 0; r < 4; ++r)
            sv[t][r] = __expf(sv[t][r] - mr[r]);
    #pragma unroll
    for (int r = 0; r < 4; ++r)
        sum[r] = sv[0][r] + sv[1][r] + sv[2][r];
    #pragma unroll
    for (int o = 1; o < 16; o <<= 1)
        #pragma unroll
        for (int r = 0; r < 4; ++r)
            sum[r] += __shfl_xor(sum[r], o, 64);
    #pragma unroll
    for (int r = 0; r < 4; ++r) {
        float inv = 1.0f / sum[r];
        #pragma unroll
        for (int t = 0; t < 3; ++t) sv[t][r] *= inv;
    }

    // ---- P -> LDS (C-layout write, A-layout read) ----
    bf16* P = &Plds[wave][0][0];
    {
        int rr = lane >> 2;
        int c0 = 48 + (lane & 3) * 4;
        *(bf16x4*)(&P[rr * 72 + c0]) = (bf16x4){(bf16)0.f, (bf16)0.f, (bf16)0.f, (bf16)0.f};
    }
    #pragma unroll
    for (int t = 0; t < 3; ++t)
        #pragma unroll
        for (int r = 0; r < 4; ++r)
            P[(quad * 4 + r) * 72 + t * 16 + l16] = (bf16)sv[t][r];
    __syncthreads();

    bf16x8 pf0 = *(const bf16x8*)(&P[l16 * 72 + quad * 8]);
    bf16x8 pf1 = *(const bf16x8*)(&P[l16 * 72 + 32 + quad * 8]);

    // ---- O = P V : Vt frags from stride-66 LDS (scalar reads, bank-free) ----
    f32x4 o[4] = {};
    #pragma unroll
    for (int t = 0; t < 4; ++t) {
        bf16x8 vf0, vf1;
        #pragma unroll
        for (int j = 0; j < 8; ++j) {
            vf0[j] = Vlds[(rel + quad * 8 + j) * 66 + t * 16 + l16];
            vf1[j] = Vlds[(rel + 32 + quad * 8 + j) * 66 + t * 16 + l16];
        }
        o[t] = __builtin_amdgcn_mfma_f32_16x16x32_bf16(pf0, vf0, o[t], 0, 0, 0);
        o[t] = __builtin_amdgcn_mfma_f32_16x16x32_bf16(pf1, vf1, o[t], 0, 0, 0);
    }

    // ---- epilogue: C-layout col = d, row = query ----
    bf16* orow = att + (rowbase + q0w) * DIM_ + h * HDIM_;
    #pragma unroll
    for (int t = 0; t < 4; ++t)
        #pragma unroll
        for (int r = 0; r < 4; ++r)
            orow[(size_t)(quad * 4 + r) * DIM_ + t * 16 + l16] = (bf16)o[t][r];
}

extern "C" void kernel_launch(void* const* d_in, const int* in_sizes, int n_in,
                              void* d_out, int out_size, void* d_ws, size_t ws_size,
                              hipStream_t stream) {
    const int n_x  = B_ * L_ * DIM_;       // 4194304
    const int n_wq = 3 * DIM_ * DIM_;      // 786432
    const int n_bq = 3 * DIM_;             // 1536
    const int n_wp = DIM_ * DIM_;          // 262144
    const int n_bp = DIM_;                 // 512

    char* ws = (char*)d_ws;
    bf16* xb  = (bf16*)ws;
    bf16* wqb = xb  + n_x;
    bf16* bqb = wqb + n_wq;
    bf16* wpb = bqb + n_bq;
    bf16* bpb = wpb + n_wp;
    bf16* qkv = bpb + n_bp;                          // 8192 x 1536
    bf16* att = qkv + (size_t)8192 * 1536;           // 8192 x 512

    float* out = (float*)d_out;
    const int M = B_ * L_;  // 8192

    cvt_all<<<2562, 256, 0, stream>>>(
        (const float*)d_in[0], (const float*)d_in[1], (const float*)d_in[2],
        (const float*)d_in[3], (const float*)d_in[4],
        xb, wqb, bqb, wpb, bpb);

    gemm_nt_bias<bf16><<<dim3(M / 128, (3 * DIM_) / 128), 256, 0, stream>>>(
        xb, wqb, bqb, qkv, M, 3 * DIM_, DIM_);

    na1d_attn_mfma<<<dim3((B_ * HEADS_ * L_) / 64), 256, 0, stream>>>(qkv, att);

    gemm_nt_bias<float><<<dim3(M / 128, DIM_ / 128), 256, 0, stream>>>(
        att, wpb, bpb, out, M, DIM_, DIM_);
}